// Round 5
// baseline (197.423 us; speedup 1.0000x reference)
//
#include <hip/hip_runtime.h>

// out = x + 0.002 * einsum('bci,bij->bcj', f, softmax_i(einsum('bci,bcj->bij', f, f)))
// x: [8, 128, 64, 64] fp32.  b=8, c=d=128, n=wh=4096.
// Flash attention, Q=K=V=Ft. One subtiled LDS tile serves BOTH operand views:
//   - PV B-frags (V^T[c][key]) via normal b128 reads
//   - QK^T A-frags (K[key][c]) via ds_read_b64_tr_b16 hardware transpose
// ws: xh = bf16(x), same [b][c][n] layout, 8 MB. No transpose kernel.

typedef __bf16 bf16;
typedef bf16 bf16x4 __attribute__((ext_vector_type(4)));
typedef bf16 bf16x8 __attribute__((ext_vector_type(8)));
typedef float f32x4 __attribute__((ext_vector_type(4)));
typedef unsigned int u32;
typedef u32 u32x4 __attribute__((ext_vector_type(4)));
typedef unsigned long long u64;

#define BATCH 8
#define CD 128
#define NN 4096
#define QBLK 64
#define KVB 64
#define NT (NN / KVB)
#define LOG2E 1.44269504f

// ---------------- kernel 1: xh = bf16(x), same layout ----------------
__global__ __launch_bounds__(256) void to_bf16(const float* __restrict__ x,
                                               bf16* __restrict__ xh) {
    const int n4 = BATCH * CD * NN / 4;
    int i = blockIdx.x * 256 + threadIdx.x;
    const int stride = gridDim.x * 256;
    for (; i < n4; i += stride) {
        f32x4 v = reinterpret_cast<const f32x4*>(x)[i];
        bf16x4 o;
#pragma unroll
        for (int e = 0; e < 4; e++) o[e] = (bf16)v[e];
        reinterpret_cast<bf16x4*>(xh)[i] = o;
    }
}

// ---------------- kernel 2: flash attention + fused residual ----------------
// 512 blocks (8 batch x 64 q-tiles), 512 threads = 8 waves.
// Wave w: q-group wq = w&3 (16 rows), key-half wk = w>>2 (32 keys).
// KV loop: 64 keys/iter, double-buffered subtiled LDS, 1 barrier/iter.
__global__ __launch_bounds__(512, 2) void attn_kernel(const float* __restrict__ x,
                                                      const bf16* __restrict__ xh,
                                                      float* __restrict__ out) {
    const int tid = threadIdx.x;
    const int w   = tid >> 6;
    const int wq  = w & 3;
    const int wk  = w >> 2;
    const int l   = tid & 63;
    const int l15 = l & 15;
    const int l4  = l >> 4;

    // XCD swizzle: blockIdx%8 = XCD -> give each XCD one full batch (L2 locality)
    const int nb    = (blockIdx.x & 7) * 64 + (blockIdx.x >> 3);
    const int batch = nb >> 6;
    const int q0    = (nb & 63) * QBLK;

    const bf16*  xhb = xh + (size_t)batch * CD * NN;
    const float* xb  = x  + (size_t)batch * CD * NN;
    float*       outb = out + (size_t)batch * CD * NN;

    __shared__ union {
        struct {
            bf16 vt2[2][8192];     // subtiled [c/4][keygrp][4c][16key], 16KB/buf
            bf16 p[8][16][40];     // per-wave P, 80B rows (bank-friendly pad)
        } s;
        struct {
            float o[2][QBLK][CD + 5];  // pair halves of O
            float mx[8][16];           // per-wave running max (log2 units)
            float ls[8][16];           // per-wave denominator
        } e;
    } sm;

    // ---- Q fragments from xh (strided scalar loads, once), scaled by log2e ----
    bf16x8 qf[4];
    {
        const int q = q0 + wq * 16 + l15;
#pragma unroll
        for (int ct = 0; ct < 4; ct++)
#pragma unroll
            for (int e = 0; e < 8; e++) {
                const int c = ct * 32 + l4 * 8 + e;
                qf[ct][e] = (bf16)((float)xhb[(size_t)c * NN + q] * LOG2E);
            }
    }

    // ---- staging: 16KB bf16 from xh into subtiled layout ----
    const int kh = tid & 7;     // key-oct: keys kh*8..+7
    const int c8 = tid >> 3;    // c 0..63 (+64 on j=1)
    bf16x8 kreg[2];
    char* vt2base = (char*)&sm.s.vt2[0][0];
    const int wbyte = ((c8 >> 2) * 4 + (kh >> 1)) * 128 + (c8 & 3) * 32 + (kh & 1) * 16;

    auto stage_load = [&](int i0) {
#pragma unroll
        for (int j = 0; j < 2; j++)
            kreg[j] = *reinterpret_cast<const bf16x8*>(
                xhb + (size_t)(j * 64 + c8) * NN + i0 + kh * 8);
    };
    auto stage_write = [&](int buf) {
#pragma unroll
        for (int j = 0; j < 2; j++)
            *reinterpret_cast<bf16x8*>(vt2base + buf * 16384 + j * 8192 + wbyte) = kreg[j];
    };

    f32x4 oacc[8];
#pragma unroll
    for (int i = 0; i < 8; i++) oacc[i] = f32x4{0.f, 0.f, 0.f, 0.f};
    float m_run = -1e30f;   // running max (log2 units) for q = l15
    float l_par = 0.0f;     // per-lane partial denominator

    const u32 vt2lds  = (u32)(uintptr_t)vt2base;
    const u32 tr_lane = vt2lds + (u32)(l4 * 1024 + l15 * 2 + wk * 256);
    const int vfl     = (l15 >> 2) * 512 + (wk * 2 + (l4 >> 1)) * 128 +
                        (l15 & 3) * 32 + (l4 & 1) * 16;

    stage_load(0);
    stage_write(0);
    __syncthreads();

    for (int it = 0; it < NT; ++it) {
        const int cur = it & 1;
        if (it + 1 < NT) stage_load((it + 1) * KVB);   // HBM latency hides under compute

        // ---- QK^T via hw-transpose reads: s[g][r] = S'[key=wk*32+g*16+l4*4+r][q=l15]
        const u32 trb = tr_lane + (u32)(cur * 16384);
        f32x4 s[2];
        __builtin_amdgcn_s_setprio(1);
#pragma unroll
        for (int g = 0; g < 2; g++) {
            u64 t0, t1, t2, t3, t4, t5, t6, t7;
            u32 a0 = trb + (u32)(g * 128);
            u32 a1 = a0 + 4096, a2 = a0 + 8192, a3 = a0 + 12288;
            asm volatile(
                "ds_read_b64_tr_b16 %0, %8\n\t"
                "ds_read_b64_tr_b16 %1, %8 offset:512\n\t"
                "ds_read_b64_tr_b16 %2, %9\n\t"
                "ds_read_b64_tr_b16 %3, %9 offset:512\n\t"
                "ds_read_b64_tr_b16 %4, %10\n\t"
                "ds_read_b64_tr_b16 %5, %10 offset:512\n\t"
                "ds_read_b64_tr_b16 %6, %11\n\t"
                "ds_read_b64_tr_b16 %7, %11 offset:512\n\t"
                "s_waitcnt lgkmcnt(0)"
                : "=v"(t0), "=v"(t1), "=v"(t2), "=v"(t3),
                  "=v"(t4), "=v"(t5), "=v"(t6), "=v"(t7)
                : "v"(a0), "v"(a1), "v"(a2), "v"(a3)
                : "memory");
            __builtin_amdgcn_sched_barrier(0);   // rule #18: keep MFMA after the wait

            u32x4 kw0 = {(u32)t0, (u32)(t0 >> 32), (u32)t1, (u32)(t1 >> 32)};
            u32x4 kw1 = {(u32)t2, (u32)(t2 >> 32), (u32)t3, (u32)(t3 >> 32)};
            u32x4 kw2 = {(u32)t4, (u32)(t4 >> 32), (u32)t5, (u32)(t5 >> 32)};
            u32x4 kw3 = {(u32)t6, (u32)(t6 >> 32), (u32)t7, (u32)(t7 >> 32)};
            f32x4 sg = {0.f, 0.f, 0.f, 0.f};
            sg = __builtin_amdgcn_mfma_f32_16x16x32_bf16(__builtin_bit_cast(bf16x8, kw0), qf[0], sg, 0, 0, 0);
            sg = __builtin_amdgcn_mfma_f32_16x16x32_bf16(__builtin_bit_cast(bf16x8, kw1), qf[1], sg, 0, 0, 0);
            sg = __builtin_amdgcn_mfma_f32_16x16x32_bf16(__builtin_bit_cast(bf16x8, kw2), qf[2], sg, 0, 0, 0);
            sg = __builtin_amdgcn_mfma_f32_16x16x32_bf16(__builtin_bit_cast(bf16x8, kw3), qf[3], sg, 0, 0, 0);
            s[g] = sg;
        }
        __builtin_amdgcn_s_setprio(0);

        // ---- softmax over this wave's 32 keys (log2 space) ----
        float mp = fmaxf(fmaxf(fmaxf(s[0][0], s[0][1]), fmaxf(s[0][2], s[0][3])),
                         fmaxf(fmaxf(s[1][0], s[1][1]), fmaxf(s[1][2], s[1][3])));
        mp = fmaxf(mp, __shfl_xor(mp, 16));
        mp = fmaxf(mp, __shfl_xor(mp, 32));

        if (__any(mp > m_run + 11.5f)) {   // defer-max (thr = 8 nats in log2)
            const float mn    = fmaxf(m_run, mp);
            const float alpha = exp2f(m_run - mn);
            m_run = mn;
            l_par *= alpha;
            const float a0_ = __shfl(alpha, l4 * 4 + 0);
            const float a1_ = __shfl(alpha, l4 * 4 + 1);
            const float a2_ = __shfl(alpha, l4 * 4 + 2);
            const float a3_ = __shfl(alpha, l4 * 4 + 3);
#pragma unroll
            for (int ct = 0; ct < 8; ct++) {
                oacc[ct][0] *= a0_; oacc[ct][1] *= a1_;
                oacc[ct][2] *= a2_; oacc[ct][3] *= a3_;
            }
        }

        float pe[2][4];
        float ps = 0.0f;
#pragma unroll
        for (int g = 0; g < 2; g++)
#pragma unroll
            for (int r = 0; r < 4; r++) {
                pe[g][r] = exp2f(s[g][r] - m_run);
                ps += pe[g][r];
            }
        l_par += ps;

        // ---- P -> wave-local LDS -> A-frag (keys local to this wave's 32) ----
        bf16x4 t4a, t4b;
#pragma unroll
        for (int r = 0; r < 4; r++) { t4a[r] = (bf16)pe[0][r]; t4b[r] = (bf16)pe[1][r]; }
        *reinterpret_cast<bf16x4*>(&sm.s.p[w][l15][l4 * 4])      = t4a;
        *reinterpret_cast<bf16x4*>(&sm.s.p[w][l15][16 + l4 * 4]) = t4b;
        bf16x8 pf = *reinterpret_cast<const bf16x8*>(&sm.s.p[w][l15][l4 * 8]);

        // ---- PV: O[q][c] partial over this wave's 32 keys, 8 MFMA ----
        const char* vtc = vt2base + cur * 16384;
        __builtin_amdgcn_s_setprio(1);
#pragma unroll
        for (int ct = 0; ct < 8; ct++) {
            bf16x8 vf = *reinterpret_cast<const bf16x8*>(vtc + ct * 2048 + vfl);
            oacc[ct] = __builtin_amdgcn_mfma_f32_16x16x32_bf16(pf, vf, oacc[ct], 0, 0, 0);
        }
        __builtin_amdgcn_s_setprio(0);

        if (it + 1 < NT) stage_write(cur ^ 1);   // vmcnt wait lands here
        __syncthreads();
    }

    // ---- epilogue: merge key-half pairs (w <-> w^4), normalize, residual ----
    float L = l_par;
    L += __shfl_xor(L, 16);
    L += __shfl_xor(L, 32);
    if (l < 16) { sm.e.mx[w][l15] = m_run; sm.e.ls[w][l15] = L; }
    __syncthreads();

    const float m_o = sm.e.mx[w ^ 4][l15];
    const float L_o = sm.e.ls[w ^ 4][l15];
    const float m_p = fmaxf(m_run, m_o);
    const float sS  = exp2f(m_run - m_p);
    const float Lt  = L * sS + L_o * exp2f(m_o - m_p);
    const float fsc = sS / Lt;
    const float f0 = __shfl(fsc, l4 * 4 + 0);
    const float f1 = __shfl(fsc, l4 * 4 + 1);
    const float f2 = __shfl(fsc, l4 * 4 + 2);
    const float f3 = __shfl(fsc, l4 * 4 + 3);
#pragma unroll
    for (int ct = 0; ct < 8; ct++) {
        sm.e.o[wk][wq * 16 + l4 * 4 + 0][ct * 16 + l15] = oacc[ct][0] * f0;
        sm.e.o[wk][wq * 16 + l4 * 4 + 1][ct * 16 + l15] = oacc[ct][1] * f1;
        sm.e.o[wk][wq * 16 + l4 * 4 + 2][ct * 16 + l15] = oacc[ct][2] * f2;
        sm.e.o[wk][wq * 16 + l4 * 4 + 3][ct * 16 + l15] = oacc[ct][3] * f3;
    }
    __syncthreads();

    // fused residual, f32x4 along q
    const int qq = (tid & 15) * 4;   // q quad
    const int cw = tid >> 4;         // 0..31
#pragma unroll
    for (int j = 0; j < 4; j++) {
        const int c = j * 32 + cw;
        f32x4 xv = *reinterpret_cast<const f32x4*>(xb + (size_t)c * NN + q0 + qq);
        f32x4 ov;
#pragma unroll
        for (int e = 0; e < 4; e++)
            ov[e] = xv[e] + 0.002f * (sm.e.o[0][qq + e][c] + sm.e.o[1][qq + e][c]);
        *reinterpret_cast<f32x4*>(outb + (size_t)c * NN + q0 + qq) = ov;
    }
}

extern "C" void kernel_launch(void* const* d_in, const int* in_sizes, int n_in,
                              void* d_out, int out_size, void* d_ws, size_t ws_size,
                              hipStream_t stream) {
    const float* x = (const float*)d_in[0];
    float* out = (float*)d_out;
    bf16* xh = (bf16*)d_ws;   // 8 MB

    to_bf16<<<2048, 256, 0, stream>>>(x, xh);
    attn_kernel<<<512, 512, 0, stream>>>(x, xh, out);
}

// Round 6
// 178.422 us; speedup vs baseline: 1.1065x; 1.1065x over previous
//
#include <hip/hip_runtime.h>

// out = x + 0.002 * einsum('bci,bij->bcj', f, softmax_i(einsum('bci,bcj->bij', f, f)))
// x: [8, 128, 64, 64] fp32.  b=8, c=d=128, n=wh=4096.
// Flash attention, Q=K=V=Ft. 32x32x16 MFMA, 32 q-rows/wave, P in registers
// (lane^32 exchange), XOR-swizzled LDS K/V tiles, XCD = batch.
// ws: ft bf16 [b][n][c] = 8 MB.

typedef __bf16 bf16;
typedef bf16 bf16x2 __attribute__((ext_vector_type(2)));
typedef bf16 bf16x4 __attribute__((ext_vector_type(4)));
typedef bf16 bf16x8 __attribute__((ext_vector_type(8)));
typedef float f32x4 __attribute__((ext_vector_type(4)));
typedef float f32x16 __attribute__((ext_vector_type(16)));
typedef unsigned int u32;
typedef u32 u32x4 __attribute__((ext_vector_type(4)));

#define BATCH 8
#define CD 128
#define NN 4096
#define QBLK 128
#define KVB 64
#define NT (NN / KVB)
#define LOG2E 1.44269504f

// XOR swizzle (T2): 16-B granule, bijective per row, same map on write & read.
#define KT_BY(row, colb) (((row) << 8) + ((colb) ^ (((row) & 7) << 4)))  // 256 B rows
#define VT_BY(row, colb) (((row) << 7) + ((colb) ^ (((row) & 7) << 4)))  // 128 B rows

// ---------- kernel 1: ft[b][n][c] = bf16(x[b][c][n]) — LDS-free transpose ----------
// One b128 of ft per thread: gather 8 strided rows (each 64B-line fully used by
// 16 neighbor lanes), pack, store (4 c8-neighbors complete each write line).
__global__ __launch_bounds__(256) void transpose_to_bf16(const float* __restrict__ x,
                                                         bf16* __restrict__ ft) {
    const u32 g  = blockIdx.x * 256 + threadIdx.x;   // 8*4096*16 = 524288 slots
    const u32 b  = g >> 16;
    const u32 r  = g & 65535;
    const u32 n_lo  = r & 15;
    const u32 c8_lo = (r >> 4) & 3;
    const u32 hi    = r >> 6;
    const u32 c8 = (hi & 3) * 4 + c8_lo;             // 0..15
    const u32 n  = (hi >> 2) * 16 + n_lo;            // 0..4095
    const float* xb = x + (size_t)b * CD * NN;
    bf16x8 o;
#pragma unroll
    for (int e = 0; e < 8; e++)
        o[e] = (bf16)xb[(size_t)(c8 * 8 + e) * NN + n];
    *reinterpret_cast<bf16x8*>(ft + ((size_t)b * NN + n) * CD + c8 * 8) = o;
}

// ---------- kernel 2: flash attention + fused residual ----------
// 256 blocks (XCD=batch, 32 q-tiles of 128), 512 threads = 8 waves (4 wq x 2 wk).
// Wave: 32 q-rows x 32 keys per iter, 16 MFMA (32x32x16), KV tile 64, dbuf LDS.
__global__ __launch_bounds__(512, 2) void attn_kernel(const float* __restrict__ x,
                                                      const bf16* __restrict__ ft,
                                                      float* __restrict__ out) {
    const int tid = threadIdx.x;
    const int w   = tid >> 6;
    const int wq  = w & 3;      // q-group: 32 rows
    const int wk  = w >> 2;     // key-half: 32 keys
    const int l   = tid & 63;
    const int l31 = l & 31;
    const int h   = l >> 5;

    const int batch = blockIdx.x & 7;            // round-robin dispatch -> XCD = batch
    const int q0    = (blockIdx.x >> 3) * QBLK;

    const bf16*  ftb  = ft  + (size_t)batch * NN * CD;
    const float* xb   = x   + (size_t)batch * CD * NN;
    float*       outb = out + (size_t)batch * CD * NN;

    __shared__ union {
        struct {
            bf16 kt[2][KVB * 128];   // [key][c] swizzled, 16 KB/buf
            bf16 vt[2][CD * 64];     // [c][key] swizzled, 16 KB/buf
        } s;
        float o[QBLK][133];          // epilogue O merge (stride 133: gcd(5,32)=1)
    } sm;
    __shared__ float s_mx[8][32], s_ls[8][32];

    // Q frags (B-operand): q = q0+wq*32+l31, c = kst*16 + h*8 + e; folded log2e
    bf16x8 qf[8];
    {
        const bf16* qp = ftb + (size_t)(q0 + wq * 32 + l31) * CD + h * 8;
#pragma unroll
        for (int kst = 0; kst < 8; kst++) {
            bf16x8 t = *reinterpret_cast<const bf16x8*>(qp + kst * 16);
#pragma unroll
            for (int e = 0; e < 8; e++) qf[kst][e] = (bf16)((float)t[e] * LOG2E);
        }
    }

    // ---- staging: kt (from ft, bf16 copy) + vt (from x, f32->bf16) ----
    bf16x8 kreg[2];
    f32x4  vreg[4];
    auto stage_load = [&](int i0) {
#pragma unroll
        for (int j = 0; j < 2; j++) {                 // kt: slot = key*16 + cs
            const int slot = tid + j * 512;
            kreg[j] = *reinterpret_cast<const bf16x8*>(
                ftb + (size_t)(i0 + (slot >> 4)) * CD + (slot & 15) * 8);
        }
#pragma unroll
        for (int j = 0; j < 4; j++) {                 // vt: slot = c*16 + kq (4 keys)
            const int slot = tid + j * 512;
            vreg[j] = *reinterpret_cast<const f32x4*>(
                xb + (size_t)(slot >> 4) * NN + i0 + (slot & 15) * 4);
        }
    };
    auto stage_write = [&](int buf) {
        char* ktb = (char*)sm.s.kt[buf];
        char* vtb = (char*)sm.s.vt[buf];
#pragma unroll
        for (int j = 0; j < 2; j++) {
            const int slot = tid + j * 512;
            *reinterpret_cast<bf16x8*>(ktb + KT_BY(slot >> 4, (slot & 15) * 16)) = kreg[j];
        }
#pragma unroll
        for (int j = 0; j < 4; j++) {
            const int slot = tid + j * 512;
            bf16x4 t;
#pragma unroll
            for (int e = 0; e < 4; e++) t[e] = (bf16)vreg[j][e];
            *reinterpret_cast<bf16x4*>(vtb + VT_BY(slot >> 4, (slot & 15) * 8)) = t;
        }
    };

    f32x16 oacc[4];
#pragma unroll
    for (int ct = 0; ct < 4; ct++)
#pragma unroll
        for (int r = 0; r < 16; r++) oacc[ct][r] = 0.0f;
    float m_run = -1e30f;   // running max (log2 units) for q = l31
    float l_par = 0.0f;     // per-lane partial denominator (this lane's 16-key share)

    stage_load(0);
    stage_write(0);
    __syncthreads();

    for (int it = 0; it < NT; ++it) {
        const int cur = it & 1;
        if (it + 1 < NT) stage_load((it + 1) * KVB);   // in flight under compute (T14)

        const char* ktb = (const char*)sm.s.kt[cur];
        const char* vtb = (const char*)sm.s.vt[cur];

        // ---- QK^T: S'[key=wk*32+rowmap][q=l31], 8 MFMA, 2 acc chains (ILP) ----
        f32x16 sA, sB;
#pragma unroll
        for (int r = 0; r < 16; r++) { sA[r] = 0.0f; sB[r] = 0.0f; }
        __builtin_amdgcn_s_setprio(1);
#pragma unroll
        for (int kst = 0; kst < 8; kst += 2) {
            bf16x8 kf0 = *reinterpret_cast<const bf16x8*>(
                ktb + KT_BY(wk * 32 + l31, kst * 32 + h * 16));
            bf16x8 kf1 = *reinterpret_cast<const bf16x8*>(
                ktb + KT_BY(wk * 32 + l31, (kst + 1) * 32 + h * 16));
            sA = __builtin_amdgcn_mfma_f32_32x32x16_bf16(kf0, qf[kst], sA, 0, 0, 0);
            sB = __builtin_amdgcn_mfma_f32_32x32x16_bf16(kf1, qf[kst + 1], sB, 0, 0, 0);
        }
        __builtin_amdgcn_s_setprio(0);
        float s[16];
#pragma unroll
        for (int r = 0; r < 16; r++) s[r] = sA[r] + sB[r];
        // lane holds k_local = wk*32 + (r&3) + 8*(r>>2) + 4*h, q = l31

        // ---- softmax over keys (log2 space), in-register ----
        float mp = s[0];
#pragma unroll
        for (int r = 1; r < 16; r++) mp = fmaxf(mp, s[r]);
        mp = fmaxf(mp, __shfl_xor(mp, 32));

        if (__any(mp > m_run + 11.5f)) {   // defer-max (T13): rescale rarely
            const float mn = fmaxf(m_run, mp);
            const float al = exp2f(m_run - mn);
            m_run = mn;
            l_par *= al;
#pragma unroll
            for (int ct = 0; ct < 4; ct++)
#pragma unroll
                for (int r = 0; r < 16; r++) oacc[ct][r] *= al;   // same q per lane: no shuffle
        }

        float pe[16];
        float ps = 0.0f;
#pragma unroll
        for (int r = 0; r < 16; r++) { pe[r] = exp2f(s[r] - m_run); ps += pe[r]; }
        l_par += ps;

        // ---- P -> PV A-frags fully in registers (lane<->lane^32 exchange) ----
        // W[g][j] packs k = 8g + 4h + {2j, 2j+1}
        u32 W[4][2], Xs[4][2];
#pragma unroll
        for (int gg = 0; gg < 4; gg++)
#pragma unroll
            for (int j = 0; j < 2; j++) {
                bf16x2 t = {(bf16)pe[4 * gg + 2 * j], (bf16)pe[4 * gg + 2 * j + 1]};
                W[gg][j] = __builtin_bit_cast(unsigned short, t[0]) |
                           ((u32)__builtin_bit_cast(unsigned short, t[1]) << 16);
                Xs[gg][j] = (u32)__shfl_xor((int)W[gg][j], 32);
            }
        // A-frag kstep s: words 0,1 = W[2s+h][j] from half 0; words 2,3 from half 1
        u32x4 pw0 = {h ? Xs[1][0] : W[0][0], h ? Xs[1][1] : W[0][1],
                     h ? W[1][0] : Xs[0][0], h ? W[1][1] : Xs[0][1]};
        u32x4 pw1 = {h ? Xs[3][0] : W[2][0], h ? Xs[3][1] : W[2][1],
                     h ? W[3][0] : Xs[2][0], h ? W[3][1] : Xs[2][1]};
        bf16x8 pa0 = __builtin_bit_cast(bf16x8, pw0);
        bf16x8 pa1 = __builtin_bit_cast(bf16x8, pw1);

        // ---- PV: O[q][c] over this wave's 32 keys, 8 MFMA, 4 chains ----
        __builtin_amdgcn_s_setprio(1);
#pragma unroll
        for (int ct = 0; ct < 4; ct++) {
            bf16x8 vf0 = *reinterpret_cast<const bf16x8*>(
                vtb + VT_BY(ct * 32 + l31, wk * 64 + h * 16));
            oacc[ct] = __builtin_amdgcn_mfma_f32_32x32x16_bf16(pa0, vf0, oacc[ct], 0, 0, 0);
            bf16x8 vf1 = *reinterpret_cast<const bf16x8*>(
                vtb + VT_BY(ct * 32 + l31, wk * 64 + 32 + h * 16));
            oacc[ct] = __builtin_amdgcn_mfma_f32_32x32x16_bf16(pa1, vf1, oacc[ct], 0, 0, 0);
        }
        __builtin_amdgcn_s_setprio(0);

        if (it + 1 < NT) stage_write(cur ^ 1);   // vmcnt wait lands here
        __syncthreads();
    }

    // ---- epilogue: merge lane pair, then wk halves; normalize; residual ----
    const float L = l_par + __shfl_xor(l_par, 32);   // m_run identical across pair
    if (l < 32) { s_mx[w][l31] = m_run; s_ls[w][l31] = L; }
    __syncthreads();
    const float m_o = s_mx[w ^ 4][l31];
    const float L_o = s_ls[w ^ 4][l31];
    const float m_p = fmaxf(m_run, m_o);
    const float eS  = exp2f(m_run - m_p);
    const float eO  = exp2f(m_o - m_p);
    const float fsc = eS / (L * eS + L_o * eO);      // per-lane, q-local

    if (wk == 0) {
#pragma unroll
        for (int ct = 0; ct < 4; ct++)
#pragma unroll
            for (int r = 0; r < 16; r++)
                sm.o[wq * 32 + l31][ct * 32 + (r & 3) + 8 * (r >> 2) + 4 * h] =
                    oacc[ct][r] * fsc;
    }
    __syncthreads();
    if (wk == 1) {
#pragma unroll
        for (int ct = 0; ct < 4; ct++)
#pragma unroll
            for (int r = 0; r < 16; r++)
                sm.o[wq * 32 + l31][ct * 32 + (r & 3) + 8 * (r >> 2) + 4 * h] +=
                    oacc[ct][r] * fsc;
    }
    __syncthreads();

    // fused residual: out[c][q] = x + 0.002*O, f32x4 along q
#pragma unroll
    for (int k = 0; k < 8; k++) {
        const int slot = tid + k * 512;          // 4096 slots: c = slot>>5, q4 = slot&31
        const int c  = slot >> 5;
        const int q4 = (slot & 31) * 4;
        f32x4 xv = *reinterpret_cast<const f32x4*>(xb + (size_t)c * NN + q0 + q4);
        f32x4 ov;
#pragma unroll
        for (int e = 0; e < 4; e++)
            ov[e] = xv[e] + 0.002f * sm.o[q4 + e][c];
        *reinterpret_cast<f32x4*>(outb + (size_t)c * NN + q0 + q4) = ov;
    }
}

extern "C" void kernel_launch(void* const* d_in, const int* in_sizes, int n_in,
                              void* d_out, int out_size, void* d_ws, size_t ws_size,
                              hipStream_t stream) {
    const float* x = (const float*)d_in[0];
    float* out = (float*)d_out;
    bf16* ft = (bf16*)d_ws;   // 8 MB

    transpose_to_bf16<<<2048, 256, 0, stream>>>(x, ft);
    attn_kernel<<<256, 512, 0, stream>>>(x, ft, out);
}